// Round 8
// baseline (298.539 us; speedup 1.0000x reference)
//
#include <hip/hip_runtime.h>

#define TT 1024
#define SS 64
#define HH 256
#define BB 4            // batches per block
#define TC 16           // timesteps per chunk
#define NC (TT / TC)    // 64 chunks

typedef _Float16 f16x8 __attribute__((ext_vector_type(8)));
typedef float    f32x4 __attribute__((ext_vector_type(4)));
typedef unsigned int u32x4 __attribute__((ext_vector_type(4)));

// ---- barrier: LDS-visibility only (no vmcnt drain; staged global loads are
// consumed from VGPRs with per-wave automatic waitcnts).
__device__ __forceinline__ void lgkm_barrier() {
    asm volatile("s_waitcnt lgkmcnt(0)" ::: "memory");
    __builtin_amdgcn_s_barrier();
}

// ---- DPP helpers (builtin path; used only in the mono fallback's p4) ----
template <int CTRL>
__device__ __forceinline__ float dpp_add(float x) {
    int v = __float_as_int(x);
    int m = __builtin_amdgcn_update_dpp(v, v, CTRL, 0xF, 0xF, true);
    return x + __int_as_float(m);
}
__device__ __forceinline__ float wxsum_row(float x) {
    x = dpp_add<0x124>(x);   // row_ror:4
    x = dpp_add<0x128>(x);   // row_ror:8
    return x;
}

// hot path: FOUR interleaved 16-lane-rowsum DPP trees; 4-inst spacing covers
// the VALU-write -> DPP-read hazard with zero s_nops.
__device__ __forceinline__ void rowsum16_x4(float& a, float& b, float& c, float& d) {
    asm volatile(
        "v_add_f32_dpp %0, %0, %0 quad_perm:[1,0,3,2] row_mask:0xf bank_mask:0xf\n\t"
        "v_add_f32_dpp %1, %1, %1 quad_perm:[1,0,3,2] row_mask:0xf bank_mask:0xf\n\t"
        "v_add_f32_dpp %2, %2, %2 quad_perm:[1,0,3,2] row_mask:0xf bank_mask:0xf\n\t"
        "v_add_f32_dpp %3, %3, %3 quad_perm:[1,0,3,2] row_mask:0xf bank_mask:0xf\n\t"
        "v_add_f32_dpp %0, %0, %0 quad_perm:[2,3,0,1] row_mask:0xf bank_mask:0xf\n\t"
        "v_add_f32_dpp %1, %1, %1 quad_perm:[2,3,0,1] row_mask:0xf bank_mask:0xf\n\t"
        "v_add_f32_dpp %2, %2, %2 quad_perm:[2,3,0,1] row_mask:0xf bank_mask:0xf\n\t"
        "v_add_f32_dpp %3, %3, %3 quad_perm:[2,3,0,1] row_mask:0xf bank_mask:0xf\n\t"
        "v_add_f32_dpp %0, %0, %0 row_half_mirror row_mask:0xf bank_mask:0xf\n\t"
        "v_add_f32_dpp %1, %1, %1 row_half_mirror row_mask:0xf bank_mask:0xf\n\t"
        "v_add_f32_dpp %2, %2, %2 row_half_mirror row_mask:0xf bank_mask:0xf\n\t"
        "v_add_f32_dpp %3, %3, %3 row_half_mirror row_mask:0xf bank_mask:0xf\n\t"
        "v_add_f32_dpp %0, %0, %0 row_mirror row_mask:0xf bank_mask:0xf\n\t"
        "v_add_f32_dpp %1, %1, %1 row_mirror row_mask:0xf bank_mask:0xf\n\t"
        "v_add_f32_dpp %2, %2, %2 row_mirror row_mask:0xf bank_mask:0xf\n\t"
        "v_add_f32_dpp %3, %3, %3 row_mirror row_mask:0xf bank_mask:0xf"
        : "+v"(a), "+v"(b), "+v"(c), "+v"(d));
}

// ============================================================================
// Kernel 1: hidden layer. Per chunk: pack spikes -> MFMA -> in-register LIF ->
// rowsum16 -> rpart; a ROTATING wave reduces the previous chunk's 8 wave-
// partials (lane-parallel, ~100cyc) and stores rsum[b][t] to global.
// No serial output scan inside the loop -> symmetric waves at the barrier.
// ============================================================================
__launch_bounds__(512, 4)
__global__ void snn_hidden(const float* __restrict__ sensor,
                           const float* __restrict__ noise,
                           const float* __restrict__ Wh,
                           const float* __restrict__ bh,
                           const float* __restrict__ Wo,
                           float* __restrict__ rsum)
{
    __shared__ __align__(16) char  spk[2][4 * 16 * 128];   // swizzled f16 spikes, 16 KB
    __shared__ __align__(16) float rpart[2][8][BB][TC];    // [buf][wave][b][t], 4 KB

    const int tid  = threadIdx.x;
    const int lane = tid & 63;
    const int wave = tid >> 6;
    const int b0   = blockIdx.x * BB;

    // ---- persistent W_h fragments: wave owns h-tiles {wave, wave+8}
    f16x8 whi[2][2], wlo[2][2];   // [nti][khalf]
    #pragma unroll
    for (int nti = 0; nti < 2; ++nti) {
        const int h = (wave + nti * 8) * 16 + (lane & 15);
        #pragma unroll
        for (int kh = 0; kh < 2; ++kh) {
            const int k = kh * 32 + (lane >> 4) * 8;
            const float* p = Wh + (size_t)h * SS + k;
            float4 wa = *(const float4*)(p);
            float4 wb = *(const float4*)(p + 4);
            float wv[8] = {wa.x, wa.y, wa.z, wa.w, wb.x, wb.y, wb.z, wb.w};
            f16x8 fh, fl;
            #pragma unroll
            for (int j = 0; j < 8; ++j) {
                _Float16 hi = (_Float16)wv[j];
                float r1 = wv[j] - (float)hi;
                fh[j] = hi;
                fl[j] = (_Float16)(r1 * 2048.0f);
            }
            whi[nti][kh] = fh; wlo[nti][kh] = fl;
        }
    }

    const int hc = lane & 15;
    const float bh0 = bh[wave * 16 + hc], bh1 = bh[128 + wave * 16 + hc];
    const float wo0 = Wo[wave * 16 + hc], wo1 = Wo[128 + wave * 16 + hc];
    const float betah = expf(-1.0f / 50.0f);
    const f32x4 zero4 = {0.0f, 0.0f, 0.0f, 0.0f};

    float vh0 = 0.0f, vh1 = 0.0f;   // hidden state: batch=lane>>4, h tiles {wave,wave+8}

    // ---- spike-writer decomposition: tid -> (tw, m, oct)
    const int wtw  = tid >> 7;
    const int wm   = (tid >> 3) & 15;
    const int woct = tid & 7;
    const int wrow = wtw * 16 + wm;
    const int wbyte = wrow * 128 + ((woct * 16) ^ ((wrow & 7) << 4));
    const float* sgp = sensor + ((size_t)(b0 + (wm >> 2)) * TT + wtw * 4 + (wm & 3)) * SS + woct * 8;
    const float* ngp = noise  + ((size_t)(b0 + (wm >> 2)) * TT + wtw * 4 + (wm & 3)) * SS + woct * 8;

    float4 sA, sB, nA, nB;   // staged next-chunk data

    auto pack_spk = [&](char* dst) {
        u32x4 sv;
        sv[0] = (nA.x < sA.x ? 0x3C00u : 0u) | (nA.y < sA.y ? 0x3C000000u : 0u);
        sv[1] = (nA.z < sA.z ? 0x3C00u : 0u) | (nA.w < sA.w ? 0x3C000000u : 0u);
        sv[2] = (nB.x < sB.x ? 0x3C00u : 0u) | (nB.y < sB.y ? 0x3C000000u : 0u);
        sv[3] = (nB.z < sB.z ? 0x3C00u : 0u) | (nB.w < sB.w ? 0x3C000000u : 0u);
        *(u32x4*)(dst + wbyte) = sv;
    };

    // lane-parallel cross-wave reduce of chunk cprev, store to rsum.
    // lane = (b = lane>>4, t = lane&15); banks: addr%32 == lane%32 -> 2-way, free.
    auto reduce_store = [&](int cprev) {
        const float* rp = &rpart[cprev & 1][0][0][0];
        const int rb = lane >> 4, rt = lane & 15;
        float s = rp[rb * TC + rt];
        #pragma unroll
        for (int w = 1; w < 8; ++w) s += rp[w * (BB * TC) + rb * TC + rt];
        rsum[(size_t)(b0 + rb) * TT + cprev * TC + rt] = s;
    };

    // ---- prologue: chunk 0 -> LDS buf0; chunk 1 -> staged regs
    sA = *(const float4*)(sgp);     sB = *(const float4*)(sgp + 4);
    nA = *(const float4*)(ngp);     nB = *(const float4*)(ngp + 4);
    pack_spk(spk[0]);
    {
        const float* ps = sgp + (size_t)1 * TC * SS;
        const float* pn = ngp + (size_t)1 * TC * SS;
        sA = *(const float4*)(ps);  sB = *(const float4*)(ps + 4);
        nA = *(const float4*)(pn);  nB = *(const float4*)(pn + 4);
    }
    lgkm_barrier();

    const int abase = hc * 128;
    const int koff0 = (((lane >> 4)    ) * 16) ^ ((hc & 7) << 4);
    const int koff1 = (((lane >> 4) + 4) * 16) ^ ((hc & 7) << 4);

    for (int c = 0; c < NC; ++c) {
        const int cur = c & 1;

        if (c + 1 < NC) pack_spk(spk[cur ^ 1]);

        if (c + 2 < NC) {
            const float* ps = sgp + (size_t)(c + 2) * TC * SS;
            const float* pn = ngp + (size_t)(c + 2) * TC * SS;
            sA = *(const float4*)(ps);  sB = *(const float4*)(ps + 4);
            nA = *(const float4*)(pn);  nB = *(const float4*)(pn + 4);
        }

        // rotating reducer wave handles chunk c-1 (lag-1; ~100 cyc extra)
        if (c > 0 && wave == (c & 7)) reduce_store(c - 1);

        // compute chunk c, software-pipelined A-frag reads
        const char* sp = spk[cur];
        f16x8 a0 = *(const f16x8*)(sp + abase + koff0);
        f16x8 a1 = *(const f16x8*)(sp + abase + koff1);
        #pragma unroll
        for (int tw = 0; tw < 4; ++tw) {
            f16x8 n0, n1;
            if (tw < 3) {
                const char* np = sp + abase + (tw + 1) * 2048;
                n0 = *(const f16x8*)(np + koff0);
                n1 = *(const f16x8*)(np + koff1);
            } else { n0 = a0; n1 = a1; }

            f32x4 ah0 = __builtin_amdgcn_mfma_f32_16x16x32_f16(a0, whi[0][0], zero4, 0, 0, 0);
            ah0       = __builtin_amdgcn_mfma_f32_16x16x32_f16(a1, whi[0][1], ah0,   0, 0, 0);
            f32x4 al0 = __builtin_amdgcn_mfma_f32_16x16x32_f16(a0, wlo[0][0], zero4, 0, 0, 0);
            al0       = __builtin_amdgcn_mfma_f32_16x16x32_f16(a1, wlo[0][1], al0,   0, 0, 0);
            f32x4 ah1 = __builtin_amdgcn_mfma_f32_16x16x32_f16(a0, whi[1][0], zero4, 0, 0, 0);
            ah1       = __builtin_amdgcn_mfma_f32_16x16x32_f16(a1, whi[1][1], ah1,   0, 0, 0);
            f32x4 al1 = __builtin_amdgcn_mfma_f32_16x16x32_f16(a0, wlo[1][0], zero4, 0, 0, 0);
            al1       = __builtin_amdgcn_mfma_f32_16x16x32_f16(a1, wlo[1][1], al1,   0, 0, 0);

            float rr[4];
            #pragma unroll
            for (int r = 0; r < 4; ++r) {
                const float d0 = __builtin_fmaf(al0[r], 0x1p-11f, ah0[r]);
                const float d1 = __builtin_fmaf(al1[r], 0x1p-11f, ah1[r]);
                vh0 = __builtin_fmaf(betah, vh0, d0) + bh0;
                vh1 = __builtin_fmaf(betah, vh1, d1) + bh1;
                const bool c0 = (vh0 >= 1.0f);
                const bool c1 = (vh1 >= 1.0f);
                rr[r] = (c0 ? wo0 : 0.0f) + (c1 ? wo1 : 0.0f);  // == s0*wo0+s1*wo1 exactly
                vh0 = c0 ? 0.0f : vh0;
                vh1 = c1 ? 0.0f : vh1;
            }
            rowsum16_x4(rr[0], rr[1], rr[2], rr[3]);

            if (hc == 0) {
                float4 rq = make_float4(rr[0], rr[1], rr[2], rr[3]);
                *(float4*)&rpart[cur][wave][lane >> 4][tw * 4] = rq;
            }
            a0 = n0; a1 = n1;
        }

        lgkm_barrier();   // LDS visibility: spk + rpart writes
    }

    // epilogue: reduce+store the final chunk
    if (wave == 0) reduce_store(NC - 1);
}

// ============================================================================
// Kernel 2: batch-parallel output LIF scan over rsum[b][t] (serial in t only).
// ============================================================================
__launch_bounds__(256, 1)
__global__ void snn_out(const float* __restrict__ rsum,
                        const float* __restrict__ bo,
                        float* __restrict__ out, int B)
{
    const int b = blockIdx.x * blockDim.x + threadIdx.x;
    if (b >= B) return;
    const float bov = bo[0];
    const float betao = expf(-1.0f / 30.0f);
    const float* rp = rsum + (size_t)b * TT;
    float vo = 0.0f, acc = 0.0f;
    for (int t = 0; t < TT; t += 4) {
        float4 q = *(const float4*)(rp + t);
        float so;
        vo = (betao * vo + q.x) + bov; so = (vo >= 1.0f) ? 1.0f : 0.0f; vo = (vo >= 1.0f) ? 0.0f : vo; acc += so;
        vo = (betao * vo + q.y) + bov; so = (vo >= 1.0f) ? 1.0f : 0.0f; vo = (vo >= 1.0f) ? 0.0f : vo; acc += so;
        vo = (betao * vo + q.z) + bov; so = (vo >= 1.0f) ? 1.0f : 0.0f; vo = (vo >= 1.0f) ? 0.0f : vo; acc += so;
        vo = (betao * vo + q.w) + bov; so = (vo >= 1.0f) ? 1.0f : 0.0f; vo = (vo >= 1.0f) ? 0.0f : vo; acc += so;
    }
    out[b] = acc * (1.0f / (float)TT);
}

// ============================================================================
// Fallback: r7 monolithic kernel (used only if ws_size < B*TT*4 bytes).
// ============================================================================
__launch_bounds__(512, 4)
__global__ void snn_mono(const float* __restrict__ sensor,
                         const float* __restrict__ noise,
                         const float* __restrict__ Wh,
                         const float* __restrict__ bh,
                         const float* __restrict__ Wo,
                         const float* __restrict__ bo,
                         float* __restrict__ out)
{
    __shared__ __align__(16) char  spk[2][4 * 16 * 128];
    __shared__ __align__(16) float rpart[2][BB][8][TC];

    const int tid  = threadIdx.x;
    const int lane = tid & 63;
    const int wave = tid >> 6;
    const int b0   = blockIdx.x * BB;

    f16x8 whi[2][2], wlo[2][2];
    #pragma unroll
    for (int nti = 0; nti < 2; ++nti) {
        const int h = (wave + nti * 8) * 16 + (lane & 15);
        #pragma unroll
        for (int kh = 0; kh < 2; ++kh) {
            const int k = kh * 32 + (lane >> 4) * 8;
            const float* p = Wh + (size_t)h * SS + k;
            float4 wa = *(const float4*)(p);
            float4 wb = *(const float4*)(p + 4);
            float wv[8] = {wa.x, wa.y, wa.z, wa.w, wb.x, wb.y, wb.z, wb.w};
            f16x8 fh, fl;
            #pragma unroll
            for (int j = 0; j < 8; ++j) {
                _Float16 hi = (_Float16)wv[j];
                float r1 = wv[j] - (float)hi;
                fh[j] = hi;
                fl[j] = (_Float16)(r1 * 2048.0f);
            }
            whi[nti][kh] = fh; wlo[nti][kh] = fl;
        }
    }

    const int hc = lane & 15;
    const float bh0 = bh[wave * 16 + hc], bh1 = bh[128 + wave * 16 + hc];
    const float wo0 = Wo[wave * 16 + hc], wo1 = Wo[128 + wave * 16 + hc];
    const float bov = bo[0];
    const float betah = expf(-1.0f / 50.0f);
    const float betao = expf(-1.0f / 30.0f);
    const f32x4 zero4 = {0.0f, 0.0f, 0.0f, 0.0f};

    float vh0 = 0.0f, vh1 = 0.0f;
    float vo = 0.0f, acc = 0.0f;

    const int wtw  = tid >> 7;
    const int wm   = (tid >> 3) & 15;
    const int woct = tid & 7;
    const int wrow = wtw * 16 + wm;
    const int wbyte = wrow * 128 + ((woct * 16) ^ ((wrow & 7) << 4));
    const float* sgp = sensor + ((size_t)(b0 + (wm >> 2)) * TT + wtw * 4 + (wm & 3)) * SS + woct * 8;
    const float* ngp = noise  + ((size_t)(b0 + (wm >> 2)) * TT + wtw * 4 + (wm & 3)) * SS + woct * 8;

    float4 sA, sB, nA, nB;

    auto pack_spk = [&](char* dst) {
        u32x4 sv;
        sv[0] = (nA.x < sA.x ? 0x3C00u : 0u) | (nA.y < sA.y ? 0x3C000000u : 0u);
        sv[1] = (nA.z < sA.z ? 0x3C00u : 0u) | (nA.w < sA.w ? 0x3C000000u : 0u);
        sv[2] = (nB.x < sB.x ? 0x3C00u : 0u) | (nB.y < sB.y ? 0x3C000000u : 0u);
        sv[3] = (nB.z < sB.z ? 0x3C00u : 0u) | (nB.w < sB.w ? 0x3C000000u : 0u);
        *(u32x4*)(dst + wbyte) = sv;
    };

    auto p4_step = [&](const float (*rp)[TC]) {
        const int wx  = (lane >> 2) & 7;
        const int twq = lane & 3;
        float4 q = *(const float4*)&rp[wx][twq * 4];
        q.x = wxsum_row(q.x); q.x += __shfl_xor(q.x, 16);
        q.y = wxsum_row(q.y); q.y += __shfl_xor(q.y, 16);
        q.z = wxsum_row(q.z); q.z += __shfl_xor(q.z, 16);
        q.w = wxsum_row(q.w); q.w += __shfl_xor(q.w, 16);
        #pragma unroll
        for (int ph = 0; ph < 4; ++ph) {
            if ((lane & 3) == ph) {
                float so;
                vo = (betao * vo + q.x) + bov; so = (vo >= 1.0f) ? 1.0f : 0.0f; vo = (vo >= 1.0f) ? 0.0f : vo; acc += so;
                vo = (betao * vo + q.y) + bov; so = (vo >= 1.0f) ? 1.0f : 0.0f; vo = (vo >= 1.0f) ? 0.0f : vo; acc += so;
                vo = (betao * vo + q.z) + bov; so = (vo >= 1.0f) ? 1.0f : 0.0f; vo = (vo >= 1.0f) ? 0.0f : vo; acc += so;
                vo = (betao * vo + q.w) + bov; so = (vo >= 1.0f) ? 1.0f : 0.0f; vo = (vo >= 1.0f) ? 0.0f : vo; acc += so;
            }
            vo  = __shfl(vo, ph);
            acc = __shfl(acc, ph);
        }
    };

    sA = *(const float4*)(sgp);     sB = *(const float4*)(sgp + 4);
    nA = *(const float4*)(ngp);     nB = *(const float4*)(ngp + 4);
    pack_spk(spk[0]);
    {
        const float* ps = sgp + (size_t)1 * TC * SS;
        const float* pn = ngp + (size_t)1 * TC * SS;
        sA = *(const float4*)(ps);  sB = *(const float4*)(ps + 4);
        nA = *(const float4*)(pn);  nB = *(const float4*)(pn + 4);
    }
    lgkm_barrier();

    const int abase = hc * 128;
    const int koff0 = (((lane >> 4)    ) * 16) ^ ((hc & 7) << 4);
    const int koff1 = (((lane >> 4) + 4) * 16) ^ ((hc & 7) << 4);

    for (int c = 0; c < NC; ++c) {
        const int cur = c & 1;
        if (c + 1 < NC) pack_spk(spk[cur ^ 1]);
        if (c + 2 < NC) {
            const float* ps = sgp + (size_t)(c + 2) * TC * SS;
            const float* pn = ngp + (size_t)(c + 2) * TC * SS;
            sA = *(const float4*)(ps);  sB = *(const float4*)(ps + 4);
            nA = *(const float4*)(pn);  nB = *(const float4*)(pn + 4);
        }
        if (c > 0 && wave < 4) p4_step(rpart[cur ^ 1][wave]);

        const char* sp = spk[cur];
        f16x8 a0 = *(const f16x8*)(sp + abase + koff0);
        f16x8 a1 = *(const f16x8*)(sp + abase + koff1);
        #pragma unroll
        for (int tw = 0; tw < 4; ++tw) {
            f16x8 n0, n1;
            if (tw < 3) {
                const char* np = sp + abase + (tw + 1) * 2048;
                n0 = *(const f16x8*)(np + koff0);
                n1 = *(const f16x8*)(np + koff1);
            } else { n0 = a0; n1 = a1; }

            f32x4 ah0 = __builtin_amdgcn_mfma_f32_16x16x32_f16(a0, whi[0][0], zero4, 0, 0, 0);
            ah0       = __builtin_amdgcn_mfma_f32_16x16x32_f16(a1, whi[0][1], ah0,   0, 0, 0);
            f32x4 al0 = __builtin_amdgcn_mfma_f32_16x16x32_f16(a0, wlo[0][0], zero4, 0, 0, 0);
            al0       = __builtin_amdgcn_mfma_f32_16x16x32_f16(a1, wlo[0][1], al0,   0, 0, 0);
            f32x4 ah1 = __builtin_amdgcn_mfma_f32_16x16x32_f16(a0, whi[1][0], zero4, 0, 0, 0);
            ah1       = __builtin_amdgcn_mfma_f32_16x16x32_f16(a1, whi[1][1], ah1,   0, 0, 0);
            f32x4 al1 = __builtin_amdgcn_mfma_f32_16x16x32_f16(a0, wlo[1][0], zero4, 0, 0, 0);
            al1       = __builtin_amdgcn_mfma_f32_16x16x32_f16(a1, wlo[1][1], al1,   0, 0, 0);

            float rr[4];
            #pragma unroll
            for (int r = 0; r < 4; ++r) {
                const float d0 = __builtin_fmaf(al0[r], 0x1p-11f, ah0[r]);
                const float d1 = __builtin_fmaf(al1[r], 0x1p-11f, ah1[r]);
                vh0 = __builtin_fmaf(betah, vh0, d0) + bh0;
                vh1 = __builtin_fmaf(betah, vh1, d1) + bh1;
                const bool c0 = (vh0 >= 1.0f);
                const bool c1 = (vh1 >= 1.0f);
                rr[r] = (c0 ? wo0 : 0.0f) + (c1 ? wo1 : 0.0f);
                vh0 = c0 ? 0.0f : vh0;
                vh1 = c1 ? 0.0f : vh1;
            }
            rowsum16_x4(rr[0], rr[1], rr[2], rr[3]);
            if (hc == 0) {
                float4 rq = make_float4(rr[0], rr[1], rr[2], rr[3]);
                *(float4*)&rpart[cur][lane >> 4][wave][tw * 4] = rq;
            }
            a0 = n0; a1 = n1;
        }
        lgkm_barrier();
    }

    if (wave < 4) {
        p4_step(rpart[(NC - 1) & 1][wave]);
        if (lane == 0) out[b0 + wave] = acc * (1.0f / (float)TT);
    }
}

extern "C" void kernel_launch(void* const* d_in, const int* in_sizes, int n_in,
                              void* d_out, int out_size, void* d_ws, size_t ws_size,
                              hipStream_t stream)
{
    const float* sensor = (const float*)d_in[0];
    const float* noise  = (const float*)d_in[1];
    const float* Wh     = (const float*)d_in[2];
    const float* bh     = (const float*)d_in[3];
    const float* Wo     = (const float*)d_in[4];
    const float* bo     = (const float*)d_in[5];
    float* out = (float*)d_out;

    const int B = in_sizes[0] / (TT * SS);   // 2048
    const size_t need = (size_t)B * TT * sizeof(float);   // 8 MB

    if (ws_size >= need) {
        float* rsum = (float*)d_ws;
        dim3 grid1(B / BB), block1(512);
        hipLaunchKernelGGL(snn_hidden, grid1, block1, 0, stream,
                           sensor, noise, Wh, bh, Wo, rsum);
        dim3 grid2((B + 255) / 256), block2(256);
        hipLaunchKernelGGL(snn_out, grid2, block2, 0, stream,
                           rsum, bo, out, B);
    } else {
        dim3 grid(B / BB), block(512);
        hipLaunchKernelGGL(snn_mono, grid, block, 0, stream,
                           sensor, noise, Wh, bh, Wo, bo, out);
    }
}

// Round 9
// 257.508 us; speedup vs baseline: 1.1593x; 1.1593x over previous
//
#include <hip/hip_runtime.h>

#define TT 1024
#define SS 64
#define HH 256
#define BB 4            // batches per block
#define TC 32           // timesteps per chunk (was 16): halves barrier count
#define NC (TT / TC)    // 32 chunks
#define NTW (TC / 4)    // 8 m-tiles per chunk

typedef _Float16 f16x8 __attribute__((ext_vector_type(8)));
typedef float    f32x4 __attribute__((ext_vector_type(4)));
typedef unsigned int u32x4 __attribute__((ext_vector_type(4)));

// ---- barrier: LDS-visibility only (no vmcnt drain; staged global loads are
// consumed from VGPRs with per-wave automatic waitcnts).
__device__ __forceinline__ void lgkm_barrier() {
    asm volatile("s_waitcnt lgkmcnt(0)" ::: "memory");
    __builtin_amdgcn_s_barrier();
}

// ---- DPP helpers (builtin path; cold p4 section) ----
template <int CTRL>
__device__ __forceinline__ float dpp_add(float x) {
    int v = __float_as_int(x);
    int m = __builtin_amdgcn_update_dpp(v, v, CTRL, 0xF, 0xF, true);
    return x + __int_as_float(m);
}
__device__ __forceinline__ float wxsum_row(float x) {
    x = dpp_add<0x124>(x);   // row_ror:4
    x = dpp_add<0x128>(x);   // row_ror:8
    return x;
}

// hot path: FOUR interleaved 16-lane-rowsum DPP trees; 4-inst spacing covers
// the VALU-write -> DPP-read hazard with zero s_nops.
__device__ __forceinline__ void rowsum16_x4(float& a, float& b, float& c, float& d) {
    asm volatile(
        "v_add_f32_dpp %0, %0, %0 quad_perm:[1,0,3,2] row_mask:0xf bank_mask:0xf\n\t"
        "v_add_f32_dpp %1, %1, %1 quad_perm:[1,0,3,2] row_mask:0xf bank_mask:0xf\n\t"
        "v_add_f32_dpp %2, %2, %2 quad_perm:[1,0,3,2] row_mask:0xf bank_mask:0xf\n\t"
        "v_add_f32_dpp %3, %3, %3 quad_perm:[1,0,3,2] row_mask:0xf bank_mask:0xf\n\t"
        "v_add_f32_dpp %0, %0, %0 quad_perm:[2,3,0,1] row_mask:0xf bank_mask:0xf\n\t"
        "v_add_f32_dpp %1, %1, %1 quad_perm:[2,3,0,1] row_mask:0xf bank_mask:0xf\n\t"
        "v_add_f32_dpp %2, %2, %2 quad_perm:[2,3,0,1] row_mask:0xf bank_mask:0xf\n\t"
        "v_add_f32_dpp %3, %3, %3 quad_perm:[2,3,0,1] row_mask:0xf bank_mask:0xf\n\t"
        "v_add_f32_dpp %0, %0, %0 row_half_mirror row_mask:0xf bank_mask:0xf\n\t"
        "v_add_f32_dpp %1, %1, %1 row_half_mirror row_mask:0xf bank_mask:0xf\n\t"
        "v_add_f32_dpp %2, %2, %2 row_half_mirror row_mask:0xf bank_mask:0xf\n\t"
        "v_add_f32_dpp %3, %3, %3 row_half_mirror row_mask:0xf bank_mask:0xf\n\t"
        "v_add_f32_dpp %0, %0, %0 row_mirror row_mask:0xf bank_mask:0xf\n\t"
        "v_add_f32_dpp %1, %1, %1 row_mirror row_mask:0xf bank_mask:0xf\n\t"
        "v_add_f32_dpp %2, %2, %2 row_mirror row_mask:0xf bank_mask:0xf\n\t"
        "v_add_f32_dpp %3, %3, %3 row_mirror row_mask:0xf bank_mask:0xf"
        : "+v"(a), "+v"(b), "+v"(c), "+v"(d));
}

__launch_bounds__(512, 4)
__global__ void snn_fused(const float* __restrict__ sensor,
                          const float* __restrict__ noise,
                          const float* __restrict__ Wh,
                          const float* __restrict__ bh,
                          const float* __restrict__ Wo,
                          const float* __restrict__ bo,
                          float* __restrict__ out)
{
    __shared__ __align__(16) char  spk[2][NTW * 16 * 128];  // swizzled f16 spikes, 2 x 16 KB
    __shared__ __align__(16) float rpart[2][BB][8][TC];     // [buf][b][wave][t], 8 KB

    const int tid  = threadIdx.x;
    const int lane = tid & 63;
    const int wave = tid >> 6;
    const int b0   = blockIdx.x * BB;

    // ---- persistent W_h fragments: wave owns h-tiles {wave, wave+8}
    f16x8 whi[2][2], wlo[2][2];   // [nti][khalf]
    #pragma unroll
    for (int nti = 0; nti < 2; ++nti) {
        const int h = (wave + nti * 8) * 16 + (lane & 15);
        #pragma unroll
        for (int kh = 0; kh < 2; ++kh) {
            const int k = kh * 32 + (lane >> 4) * 8;
            const float* p = Wh + (size_t)h * SS + k;
            float4 wa = *(const float4*)(p);
            float4 wb = *(const float4*)(p + 4);
            float wv[8] = {wa.x, wa.y, wa.z, wa.w, wb.x, wb.y, wb.z, wb.w};
            f16x8 fh, fl;
            #pragma unroll
            for (int j = 0; j < 8; ++j) {
                _Float16 hi = (_Float16)wv[j];
                float r1 = wv[j] - (float)hi;
                fh[j] = hi;
                fl[j] = (_Float16)(r1 * 2048.0f);
            }
            whi[nti][kh] = fh; wlo[nti][kh] = fl;
        }
    }

    const int hc = lane & 15;
    const float bh0 = bh[wave * 16 + hc], bh1 = bh[128 + wave * 16 + hc];
    const float wo0 = Wo[wave * 16 + hc], wo1 = Wo[128 + wave * 16 + hc];
    const float bov = bo[0];
    const float betah = expf(-1.0f / 50.0f);
    const float betao = expf(-1.0f / 30.0f);

    const f32x4 zero4 = {0.0f, 0.0f, 0.0f, 0.0f};   // persistent MFMA C operand

    float vh0 = 0.0f, vh1 = 0.0f;   // hidden state: batch=lane>>4, h tiles {wave,wave+8}
    float vo = 0.0f, acc = 0.0f;    // output state (waves 0..3 only)

    // ---- spike-writer decomposition: tid -> (tw in 0..3, m, oct); each thread
    // also covers (tw+4, m, oct). Second half: row +64 -> byte +8192, t +16.
    const int wtw  = tid >> 7;
    const int wm   = (tid >> 3) & 15;
    const int woct = tid & 7;
    const int wrow = wtw * 16 + wm;
    const int wbyte = wrow * 128 + ((woct * 16) ^ ((wrow & 7) << 4));
    const float* sgp = sensor + ((size_t)(b0 + (wm >> 2)) * TT + wtw * 4 + (wm & 3)) * SS + woct * 8;
    const float* ngp = noise  + ((size_t)(b0 + (wm >> 2)) * TT + wtw * 4 + (wm & 3)) * SS + woct * 8;

    // staged next-chunk data (prefetch regs), both 16-step halves
    float4 sA0, sB0, nA0, nB0, sA1, sB1, nA1, nB1;

    auto load_stage = [&](int c) {
        const float* ps = sgp + (size_t)c * TC * SS;
        const float* pn = ngp + (size_t)c * TC * SS;
        sA0 = *(const float4*)(ps);              sB0 = *(const float4*)(ps + 4);
        nA0 = *(const float4*)(pn);              nB0 = *(const float4*)(pn + 4);
        sA1 = *(const float4*)(ps + 16 * SS);    sB1 = *(const float4*)(ps + 16 * SS + 4);
        nA1 = *(const float4*)(pn + 16 * SS);    nB1 = *(const float4*)(pn + 16 * SS + 4);
    };

    auto pack_spk = [&](char* dst) {
        u32x4 sv;
        sv[0] = (nA0.x < sA0.x ? 0x3C00u : 0u) | (nA0.y < sA0.y ? 0x3C000000u : 0u);
        sv[1] = (nA0.z < sA0.z ? 0x3C00u : 0u) | (nA0.w < sA0.w ? 0x3C000000u : 0u);
        sv[2] = (nB0.x < sB0.x ? 0x3C00u : 0u) | (nB0.y < sB0.y ? 0x3C000000u : 0u);
        sv[3] = (nB0.z < sB0.z ? 0x3C00u : 0u) | (nB0.w < sB0.w ? 0x3C000000u : 0u);
        *(u32x4*)(dst + wbyte) = sv;
        u32x4 sw;
        sw[0] = (nA1.x < sA1.x ? 0x3C00u : 0u) | (nA1.y < sA1.y ? 0x3C000000u : 0u);
        sw[1] = (nA1.z < sA1.z ? 0x3C00u : 0u) | (nA1.w < sA1.w ? 0x3C000000u : 0u);
        sw[2] = (nB1.x < sB1.x ? 0x3C00u : 0u) | (nB1.y < sB1.y ? 0x3C000000u : 0u);
        sw[3] = (nB1.z < sB1.z ? 0x3C00u : 0u) | (nB1.w < sB1.w ? 0x3C000000u : 0u);
        *(u32x4*)(dst + wbyte + 8192) = sw;
    };

    // output-LIF step over one chunk's rpart slab (waves 0..3, batch = wave).
    // 32 timesteps: two float4 groups (t 0-15, t 16-31).
    auto p4_step = [&](const float (*rp)[TC]) {
        const int wx  = (lane >> 2) & 7;
        const int twq = lane & 3;
        float4 q1 = *(const float4*)&rp[wx][twq * 4];
        float4 q2 = *(const float4*)&rp[wx][16 + twq * 4];
        q1.x = wxsum_row(q1.x); q1.x += __shfl_xor(q1.x, 16);
        q1.y = wxsum_row(q1.y); q1.y += __shfl_xor(q1.y, 16);
        q1.z = wxsum_row(q1.z); q1.z += __shfl_xor(q1.z, 16);
        q1.w = wxsum_row(q1.w); q1.w += __shfl_xor(q1.w, 16);
        q2.x = wxsum_row(q2.x); q2.x += __shfl_xor(q2.x, 16);
        q2.y = wxsum_row(q2.y); q2.y += __shfl_xor(q2.y, 16);
        q2.z = wxsum_row(q2.z); q2.z += __shfl_xor(q2.z, 16);
        q2.w = wxsum_row(q2.w); q2.w += __shfl_xor(q2.w, 16);
        #pragma unroll
        for (int half = 0; half < 2; ++half) {
            const float4 q = half ? q2 : q1;
            #pragma unroll
            for (int ph = 0; ph < 4; ++ph) {
                if ((lane & 3) == ph) {
                    float so;
                    vo = (betao * vo + q.x) + bov; so = (vo >= 1.0f) ? 1.0f : 0.0f; vo = (vo >= 1.0f) ? 0.0f : vo; acc += so;
                    vo = (betao * vo + q.y) + bov; so = (vo >= 1.0f) ? 1.0f : 0.0f; vo = (vo >= 1.0f) ? 0.0f : vo; acc += so;
                    vo = (betao * vo + q.z) + bov; so = (vo >= 1.0f) ? 1.0f : 0.0f; vo = (vo >= 1.0f) ? 0.0f : vo; acc += so;
                    vo = (betao * vo + q.w) + bov; so = (vo >= 1.0f) ? 1.0f : 0.0f; vo = (vo >= 1.0f) ? 0.0f : vo; acc += so;
                }
                vo  = __shfl(vo, ph);
                acc = __shfl(acc, ph);
            }
        }
    };

    // ---- prologue: chunk 0 -> LDS buf0; chunk 1 -> staged regs
    load_stage(0);
    pack_spk(spk[0]);
    load_stage(1);
    lgkm_barrier();

    // A-frag addressing: row within mtile = lane&15; k-slot = lane>>4
    const int abase = hc * 128;
    const int koff0 = (((lane >> 4)    ) * 16) ^ ((hc & 7) << 4);
    const int koff1 = (((lane >> 4) + 4) * 16) ^ ((hc & 7) << 4);

    for (int c = 0; c < NC; ++c) {
        const int cur = c & 1;

        // pack chunk c+1 (staged) -> other buffer
        if (c + 1 < NC) pack_spk(spk[cur ^ 1]);

        // issue global loads for chunk c+2 (never drained at barriers)
        if (c + 2 < NC) load_stage(c + 2);

        // output LIF for chunk c-1 (lag-1; hidden by the other block on this CU)
        if (c > 0 && wave < 4) p4_step(rpart[cur ^ 1][wave]);

        // compute chunk c, software-pipelined A-frag reads
        const char* sp = spk[cur];
        f16x8 a0 = *(const f16x8*)(sp + abase + koff0);
        f16x8 a1 = *(const f16x8*)(sp + abase + koff1);
        #pragma unroll
        for (int tw = 0; tw < NTW; ++tw) {
            f16x8 n0, n1;
            if (tw < NTW - 1) {
                const char* np = sp + abase + (tw + 1) * 2048;
                n0 = *(const f16x8*)(np + koff0);
                n1 = *(const f16x8*)(np + koff1);
            } else { n0 = a0; n1 = a1; }

            f32x4 ah0 = __builtin_amdgcn_mfma_f32_16x16x32_f16(a0, whi[0][0], zero4, 0, 0, 0);
            ah0       = __builtin_amdgcn_mfma_f32_16x16x32_f16(a1, whi[0][1], ah0,   0, 0, 0);
            f32x4 al0 = __builtin_amdgcn_mfma_f32_16x16x32_f16(a0, wlo[0][0], zero4, 0, 0, 0);
            al0       = __builtin_amdgcn_mfma_f32_16x16x32_f16(a1, wlo[0][1], al0,   0, 0, 0);
            f32x4 ah1 = __builtin_amdgcn_mfma_f32_16x16x32_f16(a0, whi[1][0], zero4, 0, 0, 0);
            ah1       = __builtin_amdgcn_mfma_f32_16x16x32_f16(a1, whi[1][1], ah1,   0, 0, 0);
            f32x4 al1 = __builtin_amdgcn_mfma_f32_16x16x32_f16(a0, wlo[1][0], zero4, 0, 0, 0);
            al1       = __builtin_amdgcn_mfma_f32_16x16x32_f16(a1, wlo[1][1], al1,   0, 0, 0);

            float rr[4];
            #pragma unroll
            for (int r = 0; r < 4; ++r) {
                const float d0 = __builtin_fmaf(al0[r], 0x1p-11f, ah0[r]);
                const float d1 = __builtin_fmaf(al1[r], 0x1p-11f, ah1[r]);
                vh0 = __builtin_fmaf(betah, vh0, d0) + bh0;
                vh1 = __builtin_fmaf(betah, vh1, d1) + bh1;
                const bool c0 = (vh0 >= 1.0f);
                const bool c1 = (vh1 >= 1.0f);
                rr[r] = (c0 ? wo0 : 0.0f) + (c1 ? wo1 : 0.0f);  // == s0*wo0+s1*wo1 exactly
                vh0 = c0 ? 0.0f : vh0;
                vh1 = c1 ? 0.0f : vh1;
            }
            rowsum16_x4(rr[0], rr[1], rr[2], rr[3]);

            if (hc == 0) {
                float4 rq = make_float4(rr[0], rr[1], rr[2], rr[3]);
                *(float4*)&rpart[cur][lane >> 4][wave][tw * 4] = rq;
            }
            a0 = n0; a1 = n1;
        }

        lgkm_barrier();   // LDS visibility: spk + rpart writes
    }

    // epilogue: output LIF for the last chunk, then write results
    if (wave < 4) {
        p4_step(rpart[(NC - 1) & 1][wave]);
        if (lane == 0) out[b0 + wave] = acc * (1.0f / (float)TT);
    }
}

extern "C" void kernel_launch(void* const* d_in, const int* in_sizes, int n_in,
                              void* d_out, int out_size, void* d_ws, size_t ws_size,
                              hipStream_t stream)
{
    const float* sensor = (const float*)d_in[0];
    const float* noise  = (const float*)d_in[1];
    const float* Wh     = (const float*)d_in[2];
    const float* bh     = (const float*)d_in[3];
    const float* Wo     = (const float*)d_in[4];
    const float* bo     = (const float*)d_in[5];
    float* out = (float*)d_out;

    const int B = in_sizes[0] / (TT * SS);   // 2048
    dim3 grid(B / BB), block(512);
    hipLaunchKernelGGL(snn_fused, grid, block, 0, stream,
                       sensor, noise, Wh, bh, Wo, bo, out);
}

// Round 10
// 244.648 us; speedup vs baseline: 1.2203x; 1.0526x over previous
//
#include <hip/hip_runtime.h>

#define TT 1024
#define SS 64
#define HH 256
#define BB 4            // batches per block
#define TC 16           // timesteps per chunk
#define NC (TT / TC)    // 64 chunks

typedef _Float16 f16x8 __attribute__((ext_vector_type(8)));
typedef float    f32x4 __attribute__((ext_vector_type(4)));
typedef unsigned int u32x4 __attribute__((ext_vector_type(4)));

// ---- barrier: LDS-visibility only (no vmcnt drain; staged global loads are
// consumed from VGPRs with per-wave automatic waitcnts).
__device__ __forceinline__ void lgkm_barrier() {
    asm volatile("s_waitcnt lgkmcnt(0)" ::: "memory");
    __builtin_amdgcn_s_barrier();
}

// ---- DPP helpers (builtin path; cold p4 section) ----
template <int CTRL>
__device__ __forceinline__ float dpp_add(float x) {
    int v = __float_as_int(x);
    int m = __builtin_amdgcn_update_dpp(v, v, CTRL, 0xF, 0xF, true);
    return x + __int_as_float(m);
}
__device__ __forceinline__ float wxsum_row(float x) {
    x = dpp_add<0x124>(x);   // row_ror:4
    x = dpp_add<0x128>(x);   // row_ror:8
    return x;
}

// hot path: FOUR interleaved 16-lane-rowsum DPP trees; 4-inst spacing covers
// the VALU-write -> DPP-read hazard with zero s_nops.
__device__ __forceinline__ void rowsum16_x4(float& a, float& b, float& c, float& d) {
    asm volatile(
        "v_add_f32_dpp %0, %0, %0 quad_perm:[1,0,3,2] row_mask:0xf bank_mask:0xf\n\t"
        "v_add_f32_dpp %1, %1, %1 quad_perm:[1,0,3,2] row_mask:0xf bank_mask:0xf\n\t"
        "v_add_f32_dpp %2, %2, %2 quad_perm:[1,0,3,2] row_mask:0xf bank_mask:0xf\n\t"
        "v_add_f32_dpp %3, %3, %3 quad_perm:[1,0,3,2] row_mask:0xf bank_mask:0xf\n\t"
        "v_add_f32_dpp %0, %0, %0 quad_perm:[2,3,0,1] row_mask:0xf bank_mask:0xf\n\t"
        "v_add_f32_dpp %1, %1, %1 quad_perm:[2,3,0,1] row_mask:0xf bank_mask:0xf\n\t"
        "v_add_f32_dpp %2, %2, %2 quad_perm:[2,3,0,1] row_mask:0xf bank_mask:0xf\n\t"
        "v_add_f32_dpp %3, %3, %3 quad_perm:[2,3,0,1] row_mask:0xf bank_mask:0xf\n\t"
        "v_add_f32_dpp %0, %0, %0 row_half_mirror row_mask:0xf bank_mask:0xf\n\t"
        "v_add_f32_dpp %1, %1, %1 row_half_mirror row_mask:0xf bank_mask:0xf\n\t"
        "v_add_f32_dpp %2, %2, %2 row_half_mirror row_mask:0xf bank_mask:0xf\n\t"
        "v_add_f32_dpp %3, %3, %3 row_half_mirror row_mask:0xf bank_mask:0xf\n\t"
        "v_add_f32_dpp %0, %0, %0 row_mirror row_mask:0xf bank_mask:0xf\n\t"
        "v_add_f32_dpp %1, %1, %1 row_mirror row_mask:0xf bank_mask:0xf\n\t"
        "v_add_f32_dpp %2, %2, %2 row_mirror row_mask:0xf bank_mask:0xf\n\t"
        "v_add_f32_dpp %3, %3, %3 row_mirror row_mask:0xf bank_mask:0xf"
        : "+v"(a), "+v"(b), "+v"(c), "+v"(d));
}

__launch_bounds__(512, 4)
__global__ void snn_fused(const float* __restrict__ sensor,
                          const float* __restrict__ noise,
                          const float* __restrict__ Wh,
                          const float* __restrict__ bh,
                          const float* __restrict__ Wo,
                          const float* __restrict__ bo,
                          float* __restrict__ out)
{
    __shared__ __align__(16) char  spk[2][4 * 16 * 128];   // swizzled f16 spikes, 16 KB
    __shared__ __align__(16) float rpart[2][BB][8][TC];    // [buf][b][wave][t], 4 KB

    const int tid  = threadIdx.x;
    const int lane = tid & 63;
    const int wave = tid >> 6;
    const int b0   = blockIdx.x * BB;

    // ---- persistent W_h fragments: wave owns h-tiles {wave, wave+8}
    f16x8 whi[2][2], wlo[2][2];   // [nti][khalf]
    #pragma unroll
    for (int nti = 0; nti < 2; ++nti) {
        const int h = (wave + nti * 8) * 16 + (lane & 15);
        #pragma unroll
        for (int kh = 0; kh < 2; ++kh) {
            const int k = kh * 32 + (lane >> 4) * 8;
            const float* p = Wh + (size_t)h * SS + k;
            float4 wa = *(const float4*)(p);
            float4 wb = *(const float4*)(p + 4);
            float wv[8] = {wa.x, wa.y, wa.z, wa.w, wb.x, wb.y, wb.z, wb.w};
            f16x8 fh, fl;
            #pragma unroll
            for (int j = 0; j < 8; ++j) {
                _Float16 hi = (_Float16)wv[j];
                float r1 = wv[j] - (float)hi;
                fh[j] = hi;
                fl[j] = (_Float16)(r1 * 2048.0f);
            }
            whi[nti][kh] = fh; wlo[nti][kh] = fl;
        }
    }

    const int hc = lane & 15;
    const float bh0 = bh[wave * 16 + hc], bh1 = bh[128 + wave * 16 + hc];
    const float wo0 = Wo[wave * 16 + hc], wo1 = Wo[128 + wave * 16 + hc];
    const float bov = bo[0];
    const float betah = expf(-1.0f / 50.0f);
    const float betao = expf(-1.0f / 30.0f);

    const f32x4 zero4 = {0.0f, 0.0f, 0.0f, 0.0f};   // persistent MFMA C operand

    float vh0 = 0.0f, vh1 = 0.0f;   // hidden state: batch=lane>>4, h tiles {wave,wave+8}
    float vo = 0.0f, acc = 0.0f;    // output state (waves 0..3 only)

    // ---- spike-writer decomposition: tid -> (tw, m, oct)
    const int wtw  = tid >> 7;          // 0..3
    const int wm   = (tid >> 3) & 15;   // m = b*4 + tq
    const int woct = tid & 7;
    const int wrow = wtw * 16 + wm;
    const int wbyte = wrow * 128 + ((woct * 16) ^ ((wrow & 7) << 4));
    const float* sgp = sensor + ((size_t)(b0 + (wm >> 2)) * TT + wtw * 4 + (wm & 3)) * SS + woct * 8;
    const float* ngp = noise  + ((size_t)(b0 + (wm >> 2)) * TT + wtw * 4 + (wm & 3)) * SS + woct * 8;

    // staged next-chunk data (prefetch regs)
    float4 sA, sB, nA, nB;

    // integer spike pack: u16 one = 0x3C00 (f16 1.0); no cvt chain
    auto pack_spk = [&](char* dst) {
        u32x4 sv;
        sv[0] = (nA.x < sA.x ? 0x3C00u : 0u) | (nA.y < sA.y ? 0x3C000000u : 0u);
        sv[1] = (nA.z < sA.z ? 0x3C00u : 0u) | (nA.w < sA.w ? 0x3C000000u : 0u);
        sv[2] = (nB.x < sB.x ? 0x3C00u : 0u) | (nB.y < sB.y ? 0x3C000000u : 0u);
        sv[3] = (nB.z < sB.z ? 0x3C00u : 0u) | (nB.w < sB.w ? 0x3C000000u : 0u);
        *(u32x4*)(dst + wbyte) = sv;
    };

    // output-LIF step over one chunk's rpart slab (waves 0..3, batch = wave)
    auto p4_step = [&](const float (*rp)[TC]) {
        const int wx  = (lane >> 2) & 7;
        const int twq = lane & 3;
        float4 q = *(const float4*)&rp[wx][twq * 4];
        q.x = wxsum_row(q.x); q.x += __shfl_xor(q.x, 16);
        q.y = wxsum_row(q.y); q.y += __shfl_xor(q.y, 16);
        q.z = wxsum_row(q.z); q.z += __shfl_xor(q.z, 16);
        q.w = wxsum_row(q.w); q.w += __shfl_xor(q.w, 16);
        #pragma unroll
        for (int ph = 0; ph < 4; ++ph) {
            if ((lane & 3) == ph) {
                float so;
                vo = (betao * vo + q.x) + bov; so = (vo >= 1.0f) ? 1.0f : 0.0f; vo = (vo >= 1.0f) ? 0.0f : vo; acc += so;
                vo = (betao * vo + q.y) + bov; so = (vo >= 1.0f) ? 1.0f : 0.0f; vo = (vo >= 1.0f) ? 0.0f : vo; acc += so;
                vo = (betao * vo + q.z) + bov; so = (vo >= 1.0f) ? 1.0f : 0.0f; vo = (vo >= 1.0f) ? 0.0f : vo; acc += so;
                vo = (betao * vo + q.w) + bov; so = (vo >= 1.0f) ? 1.0f : 0.0f; vo = (vo >= 1.0f) ? 0.0f : vo; acc += so;
            }
            vo  = __shfl(vo, ph);
            acc = __shfl(acc, ph);
        }
    };

    // ---- prologue: chunk 0 -> LDS buf0; chunk 1 -> staged regs
    sA = *(const float4*)(sgp);     sB = *(const float4*)(sgp + 4);
    nA = *(const float4*)(ngp);     nB = *(const float4*)(ngp + 4);
    pack_spk(spk[0]);
    {
        const float* ps = sgp + (size_t)1 * TC * SS;
        const float* pn = ngp + (size_t)1 * TC * SS;
        sA = *(const float4*)(ps);  sB = *(const float4*)(ps + 4);
        nA = *(const float4*)(pn);  nB = *(const float4*)(pn + 4);
    }
    lgkm_barrier();

    // A-frag addressing: row within mtile = lane&15; k-slot = lane>>4
    const int abase = hc * 128;
    const int koff0 = (((lane >> 4)    ) * 16) ^ ((hc & 7) << 4);
    const int koff1 = (((lane >> 4) + 4) * 16) ^ ((hc & 7) << 4);

    for (int c = 0; c < NC; ++c) {
        const int cur = c & 1;

        // pack chunk c+1 (staged) -> other buffer
        if (c + 1 < NC) pack_spk(spk[cur ^ 1]);

        // issue global loads for chunk c+2 (never drained at barriers;
        // consumed from VGPRs next iteration via per-wave waitcnts)
        if (c + 2 < NC) {
            const float* ps = sgp + (size_t)(c + 2) * TC * SS;
            const float* pn = ngp + (size_t)(c + 2) * TC * SS;
            sA = *(const float4*)(ps);  sB = *(const float4*)(ps + 4);
            nA = *(const float4*)(pn);  nB = *(const float4*)(pn + 4);
        }

        // output LIF for chunk c-1 (lag-1)
        if (c > 0 && wave < 4) p4_step(rpart[cur ^ 1][wave]);

        // compute chunk c, software-pipelined A-frag reads
        const char* sp = spk[cur];
        f16x8 a0 = *(const f16x8*)(sp + abase + koff0);
        f16x8 a1 = *(const f16x8*)(sp + abase + koff1);
        #pragma unroll
        for (int tw = 0; tw < 4; ++tw) {
            f16x8 n0, n1;
            if (tw < 3) {
                const char* np = sp + abase + (tw + 1) * 2048;
                n0 = *(const f16x8*)(np + koff0);
                n1 = *(const f16x8*)(np + koff1);
            } else { n0 = a0; n1 = a1; }

            f32x4 ah0 = __builtin_amdgcn_mfma_f32_16x16x32_f16(a0, whi[0][0], zero4, 0, 0, 0);
            ah0       = __builtin_amdgcn_mfma_f32_16x16x32_f16(a1, whi[0][1], ah0,   0, 0, 0);
            f32x4 al0 = __builtin_amdgcn_mfma_f32_16x16x32_f16(a0, wlo[0][0], zero4, 0, 0, 0);
            al0       = __builtin_amdgcn_mfma_f32_16x16x32_f16(a1, wlo[0][1], al0,   0, 0, 0);
            f32x4 ah1 = __builtin_amdgcn_mfma_f32_16x16x32_f16(a0, whi[1][0], zero4, 0, 0, 0);
            ah1       = __builtin_amdgcn_mfma_f32_16x16x32_f16(a1, whi[1][1], ah1,   0, 0, 0);
            f32x4 al1 = __builtin_amdgcn_mfma_f32_16x16x32_f16(a0, wlo[1][0], zero4, 0, 0, 0);
            al1       = __builtin_amdgcn_mfma_f32_16x16x32_f16(a1, wlo[1][1], al1,   0, 0, 0);

            // serial LIF chain produces rr[0..3] (rr[0] earliest), then the
            // interleaved DPP block reduces all four at once, hazard-free.
            float rr[4];
            #pragma unroll
            for (int r = 0; r < 4; ++r) {
                const float d0 = __builtin_fmaf(al0[r], 0x1p-11f, ah0[r]);
                const float d1 = __builtin_fmaf(al1[r], 0x1p-11f, ah1[r]);
                vh0 = __builtin_fmaf(betah, vh0, d0) + bh0;
                vh1 = __builtin_fmaf(betah, vh1, d1) + bh1;
                const bool c0 = (vh0 >= 1.0f);
                const bool c1 = (vh1 >= 1.0f);
                rr[r] = (c0 ? wo0 : 0.0f) + (c1 ? wo1 : 0.0f);  // == s0*wo0+s1*wo1 exactly
                vh0 = c0 ? 0.0f : vh0;
                vh1 = c1 ? 0.0f : vh1;
            }
            rowsum16_x4(rr[0], rr[1], rr[2], rr[3]);

            if (hc == 0) {
                float4 rq = make_float4(rr[0], rr[1], rr[2], rr[3]);
                *(float4*)&rpart[cur][lane >> 4][wave][tw * 4] = rq;
            }
            a0 = n0; a1 = n1;
        }

        lgkm_barrier();   // LDS visibility only: spk + rpart writes
    }

    // epilogue: output LIF for the last chunk, then write results
    if (wave < 4) {
        p4_step(rpart[(NC - 1) & 1][wave]);
        if (lane == 0) out[b0 + wave] = acc * (1.0f / (float)TT);
    }
}

extern "C" void kernel_launch(void* const* d_in, const int* in_sizes, int n_in,
                              void* d_out, int out_size, void* d_ws, size_t ws_size,
                              hipStream_t stream)
{
    const float* sensor = (const float*)d_in[0];
    const float* noise  = (const float*)d_in[1];
    const float* Wh     = (const float*)d_in[2];
    const float* bh     = (const float*)d_in[3];
    const float* Wo     = (const float*)d_in[4];
    const float* bo     = (const float*)d_in[5];
    float* out = (float*)d_out;

    const int B = in_sizes[0] / (TT * SS);   // 2048
    dim3 grid(B / BB), block(512);
    hipLaunchKernelGGL(snn_fused, grid, block, 0, stream,
                       sensor, noise, Wh, bh, Wo, bo, out);
}